// Round 1
// 3311.873 us; speedup vs baseline: 1.2186x; 1.2186x over previous
//
#include <hip/hip_runtime.h>

#define BH 64
#define KLEN 4096
#define QLEN 512
#define DIM 128
#define RP 32
#define NSWEEP 6

// ---------------- Gram partials: Gpart[c] = Kc^T Kc over chunk c, Spart[c] = col sums ----------------
__global__ __launch_bounds__(256) void gram_kernel(const float* __restrict__ K,
                                                   float* __restrict__ Gpart,
                                                   float* __restrict__ Spart) {
    int bh = blockIdx.y, chunk = blockIdx.x;                  // 4 chunks of 1024 rows
    const float* Kb = K + ((size_t)bh * KLEN + (size_t)chunk * 1024) * DIM;
    __shared__ float Kt[32][129];                             // +1 pad: conflict-free column sums
    int t = threadIdx.x;
    int ty = t >> 4, tx = t & 15;                             // 16x16 threads, each 8x8 tile of C
    float acc[8][8];
#pragma unroll
    for (int i = 0; i < 8; i++)
#pragma unroll
        for (int j = 0; j < 8; j++) acc[i][j] = 0.f;
    float s_acc = 0.f;
    for (int tile = 0; tile < 32; tile++) {
        __syncthreads();
        for (int k = 0; k < 16; k++) {                        // load 32x128 coalesced
            int idx = t + k * 256;
            Kt[idx >> 7][idx & 127] = Kb[tile * 32 * DIM + idx];
        }
        __syncthreads();
#pragma unroll 4
        for (int r = 0; r < 32; r++) {
            float a_[8], b_[8];
#pragma unroll
            for (int i = 0; i < 8; i++) a_[i] = Kt[r][ty * 8 + i];
#pragma unroll
            for (int j = 0; j < 8; j++) b_[j] = Kt[r][tx * 8 + j];
#pragma unroll
            for (int i = 0; i < 8; i++)
#pragma unroll
                for (int j = 0; j < 8; j++) acc[i][j] += a_[i] * b_[j];
        }
        if (t < 128) { float ss = 0.f; for (int r = 0; r < 32; r++) ss += Kt[r][t]; s_acc += ss; }
    }
    // plain stores into this chunk's private slab — no atomics, no zero-init needed
    float* Gb = Gpart + ((size_t)chunk * BH + bh) * DIM * DIM;
#pragma unroll
    for (int i = 0; i < 8; i++)
#pragma unroll
        for (int j = 0; j < 8; j++) Gb[(ty * 8 + i) * DIM + tx * 8 + j] = acc[i][j];
    if (t < 128) Spart[((size_t)chunk * BH + bh) * DIM + t] = s_acc;
}

// ---------------- Jacobi eigensolver on C = sum_c Gpart - S S^T / n, top-32 basis -> Bout ----------------
__global__ __launch_bounds__(1024) void jacobi_kernel(const float* __restrict__ Gpart,
                                                      const float* __restrict__ Spart,
                                                      float* __restrict__ Bout) {
    __shared__ float C[128][129];   // +1 pad
    __shared__ float Vm[128][129];
    __shared__ int   pA[2][64], qA[2][64];
    __shared__ float cA[2][64], sA[2][64];
    __shared__ float diag[128];     // also used as summed-S at load time
    int bh = blockIdx.x, t = threadIdx.x;
    const size_t gslab = (size_t)BH * DIM * DIM;
    const float* Gb = Gpart + (size_t)bh * DIM * DIM;

    if (t < 128) {
        float s = 0.f;
#pragma unroll
        for (int c = 0; c < 4; c++) s += Spart[((size_t)c * BH + bh) * DIM + t];
        diag[t] = s;
    }
    __syncthreads();
    for (int k = 0; k < 16; k++) {
        int idx = t + k * 1024;
        int i = idx >> 7, j = idx & 127;
        float g = Gb[idx] + Gb[gslab + idx] + Gb[2 * gslab + idx] + Gb[3 * gslab + idx];
        C[i][j] = g - diag[i] * diag[j] * (1.0f / 4096.0f);
        Vm[i][j] = (i == j) ? 1.0f : 0.0f;
    }
    __syncthreads();
    // prologue: angles for round 0 into buffer 0
    if (t < 64) {
        int p, q;
        if (t == 0) { p = 127; q = 0; }
        else { p = t % 127; q = (127 - t) % 127; }
        float app = C[p][p], aqq = C[q][q], apq = C[p][q];
        float c = 1.0f, s = 0.0f;
        if (apq != 0.0f) {
            float tau = (aqq - app) / (2.0f * apq);
            float root = sqrtf(1.0f + tau * tau);
            float tt = (tau >= 0.0f) ? 1.0f / (tau + root) : 1.0f / (tau - root);
            c = 1.0f / sqrtf(1.0f + tt * tt);
            s = tt * c;
        }
        pA[0][t] = p; qA[0][t] = q; cA[0][t] = c; sA[0][t] = s;
    }
    __syncthreads();

    const int NR = NSWEEP * 127;
    for (int sr = 0; sr < NR; sr++) {
        int cur = sr & 1, nxt = cur ^ 1;
        // ---- phase A: sandwich C with angles[cur]; 4096 disjoint 2x2 block tasks ----
        {
            int i = t & 63, jb = (t >> 6) << 2;      // jb wave-uniform
            int pi = pA[cur][i], qi = qA[cur][i];
            float ci = cA[cur][i], si = sA[cur][i];
#pragma unroll
            for (int jj = 0; jj < 4; jj++) {
                int j = jb + jj;
                int pj = pA[cur][j], qj = qA[cur][j];
                float cj = cA[cur][j], sj = sA[cur][j];
                float a = C[pi][pj], b = C[pi][qj], d = C[qi][pj], e = C[qi][qj];
                float a1 = cj * a - sj * b, b1 = sj * a + cj * b;
                float d1 = cj * d - sj * e, e1 = sj * d + cj * e;
                C[pi][pj] = ci * a1 - si * d1;
                C[qi][pj] = si * a1 + ci * d1;
                C[pi][qj] = ci * b1 - si * e1;
                C[qi][qj] = si * b1 + ci * e1;
            }
        }
        __syncthreads();
        // ---- phase B: Vm column rotations (waves 1..15) || next-round angles (wave 0) ----
        if (t < 64) {
            if (sr + 1 < NR) {
                int r = (sr + 1) % 127;
                int p, q;
                if (t == 0) { p = 127; q = r; }
                else { p = (r + t) % 127; q = (r + 127 - t) % 127; }
                float app = C[p][p], aqq = C[q][q], apq = C[p][q];
                float c = 1.0f, s = 0.0f;
                if (apq != 0.0f) {
                    float tau = (aqq - app) / (2.0f * apq);
                    float root = sqrtf(1.0f + tau * tau);
                    float tt = (tau >= 0.0f) ? 1.0f / (tau + root) : 1.0f / (tau - root);
                    c = 1.0f / sqrtf(1.0f + tt * tt);
                    s = tt * c;
                }
                pA[nxt][t] = p; qA[nxt][t] = q; cA[nxt][t] = c; sA[nxt][t] = s;
            }
        } else {
            int tt = t - 64;
            for (int tau = tt; tau < 8192; tau += 960) {
                int j2 = tau & 63, k = tau >> 6;
                int pj = pA[cur][j2], qj = qA[cur][j2];
                float cj = cA[cur][j2], sj = sA[cur][j2];
                float x = Vm[k][pj], y = Vm[k][qj];
                Vm[k][pj] = cj * x - sj * y;
                Vm[k][qj] = sj * x + cj * y;
            }
        }
        __syncthreads();
    }

    if (t < 128) diag[t] = C[t][t];
    __syncthreads();
    if (t < 128) {   // rank-select top-32 eigenvalues; order within top-32 irrelevant (projector)
        float dt = diag[t];
        int rank = 0;
        for (int j = 0; j < 128; j++) {
            float dj = diag[j];
            rank += (dj > dt) || (dj == dt && j < t);
        }
        if (rank < RP) {
            float* Bb = Bout + (size_t)bh * DIM * RP;
            for (int k = 0; k < 128; k++) Bb[k * RP + rank] = Vm[k][t];
        }
    }
}

// ---------------- projection: Y[row][r] = sum_k X[row][k] * B[k][r] ----------------
__global__ __launch_bounds__(256) void proj_kernel(const float* __restrict__ X,
                                                   const float* __restrict__ Bmat,
                                                   float* __restrict__ Y, int nrows) {
    int bh = blockIdx.y, rb = blockIdx.x;
    __shared__ float Bl[128][33];
    __shared__ float Xt[64][129];
    int t = threadIdx.x;
    for (int k = 0; k < 16; k++) {
        int idx = t + k * 256;
        Bl[idx >> 5][idx & 31] = Bmat[(size_t)bh * DIM * RP + idx];
    }
    const float* Xb = X + ((size_t)bh * nrows + (size_t)rb * 64) * DIM;
    for (int k = 0; k < 32; k++) {
        int idx = t + k * 256;
        Xt[idx >> 7][idx & 127] = Xb[idx];
    }
    __syncthreads();
    int row = t >> 2, rg = (t & 3) * 8;
    float acc[8] = {0.f, 0.f, 0.f, 0.f, 0.f, 0.f, 0.f, 0.f};
    for (int k = 0; k < 128; k++) {
        float xv = Xt[row][k];
#pragma unroll
        for (int rr = 0; rr < 8; rr++) acc[rr] += xv * Bl[k][rg + rr];
    }
    float* Yb = Y + ((size_t)bh * nrows + (size_t)rb * 64) * RP + row * RP + rg;
#pragma unroll
    for (int rr = 0; rr < 8; rr++) Yb[rr] = acc[rr];
}

// ---------------- fused flash-style attention: softmax(Qp Kp^T * scale) @ V ----------------
// Rework vs previous round:
//  * kv ownership j = jj*4 + g  -> Kpl b128 reads hit 4 distinct bank quads (was 4-way conflict)
//  * dim ownership d = i4*16+g*4 -> Vt b128 reads conflict-free (was 4-way conflict)
//  * softmax fully in registers, row-reduce via __shfl_xor over the 4 g-lanes (serial t<64 section gone)
//  * V staged in 32-row quarter tiles -> LDS 69120 B -> 2 blocks/CU (was 117 KB, 1 block/CU)
__global__ __launch_bounds__(256, 2) void attn_kernel(const float* __restrict__ Qp,
                                                      const float* __restrict__ Kp,
                                                      const float* __restrict__ Vg,
                                                      float* __restrict__ Out) {
    const float SCALE = 0.1767766953f;  // 1/sqrt(32)
    int qt = blockIdx.x, bh = blockIdx.y;
    __shared__ float Kpl[128][36];      // rows of 32 floats, stride 36 (144 B, 16B aligned)
    __shared__ float Vt[32][132];       // quarter V tile, stride 132 (528 B, 16B aligned)
    __shared__ float Sl[64][132];       // weights exchange, (4q+j)%32 banks -> 2-way max
    int t = threadIdx.x;
    int q = t >> 2, g = t & 3;          // 64 queries x 4 lanes per query
    float qreg[32];
    const float* Qb = Qp + ((size_t)bh * QLEN + (size_t)qt * 64 + q) * RP;
#pragma unroll
    for (int r = 0; r < 32; r++) qreg[r] = Qb[r];
    float acc[32];                      // dims d = i4*16 + g*4 + c
#pragma unroll
    for (int i = 0; i < 32; i++) acc[i] = 0.f;
    float m_run = -INFINITY, l_run = 0.0f;   // replicated across the 4 g-lanes

    for (int kt = 0; kt < 32; kt++) {
        __syncthreads();
        const float4* Kpb = (const float4*)(Kp + ((size_t)bh * KLEN + (size_t)kt * 128) * RP);
        for (int k = 0; k < 4; k++) {
            int idx4 = t + k * 256;
            int j = idx4 >> 3, r4 = idx4 & 7;
            *(float4*)&Kpl[j][r4 * 4] = Kpb[idx4];
        }
        __syncthreads();
        // ---- scores in registers: thread (q,g) owns kv j = jj*4+g ----
        float sreg[32];
#pragma unroll
        for (int jj = 0; jj < 32; jj++) {
            int j = jj * 4 + g;
            float s = 0.f;
#pragma unroll
            for (int r4 = 0; r4 < 8; r4++) {
                float4 kv = *(const float4*)&Kpl[j][r4 * 4];
                s += qreg[r4 * 4 + 0] * kv.x + qreg[r4 * 4 + 1] * kv.y
                   + qreg[r4 * 4 + 2] * kv.z + qreg[r4 * 4 + 3] * kv.w;
            }
            sreg[jj] = s * SCALE;
        }
        // ---- online softmax, register + 4-lane shuffle reduce ----
        float mx = sreg[0];
#pragma unroll
        for (int jj = 1; jj < 32; jj++) mx = fmaxf(mx, sreg[jj]);
        mx = fmaxf(mx, __shfl_xor(mx, 1));
        mx = fmaxf(mx, __shfl_xor(mx, 2));
        float m_new = fmaxf(m_run, mx);
        float alpha = __expf(m_run - m_new);    // first tile: exp(-inf)=0
        float psum = 0.f;
#pragma unroll
        for (int jj = 0; jj < 32; jj++) {
            float w = __expf(sreg[jj] - m_new);
            sreg[jj] = w;
            psum += w;
        }
        psum += __shfl_xor(psum, 1);
        psum += __shfl_xor(psum, 2);
        l_run = l_run * alpha + psum;
        m_run = m_new;
        // publish weights for the kv<->dim exchange
#pragma unroll
        for (int jj = 0; jj < 32; jj++) Sl[q][jj * 4 + g] = sreg[jj];
#pragma unroll
        for (int i = 0; i < 32; i++) acc[i] *= alpha;
        // ---- PV: V staged in 4 quarter-tiles of 32 kv rows ----
        for (int ss = 0; ss < 4; ss++) {
            __syncthreads();   // (also covers Sl visibility on ss==0)
            const float4* Vb = (const float4*)(Vg + ((size_t)bh * KLEN + (size_t)kt * 128 + (size_t)ss * 32) * DIM);
            for (int k = 0; k < 4; k++) {
                int idx4 = t + k * 256;
                int j = idx4 >> 5, c4 = idx4 & 31;
                *(float4*)&Vt[j][c4 * 4] = Vb[idx4];
            }
            __syncthreads();
            for (int j = 0; j < 32; j++) {
                float w = Sl[q][ss * 32 + j];
#pragma unroll
                for (int i4 = 0; i4 < 8; i4++) {
                    float4 vv = *(const float4*)&Vt[j][i4 * 16 + g * 4];
                    acc[i4 * 4 + 0] += w * vv.x;
                    acc[i4 * 4 + 1] += w * vv.y;
                    acc[i4 * 4 + 2] += w * vv.z;
                    acc[i4 * 4 + 3] += w * vv.w;
                }
            }
        }
    }
    float linv = 1.0f / l_run;
    float* Ob = Out + ((size_t)bh * QLEN + (size_t)qt * 64 + q) * DIM;
#pragma unroll
    for (int i4 = 0; i4 < 8; i4++) {
        float4 o;
        o.x = acc[i4 * 4 + 0] * linv;
        o.y = acc[i4 * 4 + 1] * linv;
        o.z = acc[i4 * 4 + 2] * linv;
        o.w = acc[i4 * 4 + 3] * linv;
        *(float4*)&Ob[i4 * 16 + g * 4] = o;
    }
}

extern "C" void kernel_launch(void* const* d_in, const int* in_sizes, int n_in,
                              void* d_out, int out_size, void* d_ws, size_t ws_size,
                              hipStream_t stream) {
    const float* Q = (const float*)d_in[0];
    const float* K = (const float*)d_in[1];
    const float* V = (const float*)d_in[2];
    float* out = (float*)d_out;
    float* ws = (float*)d_ws;
    // workspace layout (floats):
    //   G 1048576 | S 8192 | B 262144 | Kp 8388608 | Qp 1048576   (same 43 MB footprint as before)
    // Gram partials (4 slabs G + 4 slabs S = 4227072 floats) live INSIDE the Kp region,
    // which is only written later by proj_kernel — no extra workspace needed, no atomics, no zeroing.
    float* G  = ws;                                   // unused this round (kept for layout stability)
    float* S  = G + (size_t)BH * DIM * DIM;
    float* Bm = S + BH * DIM;
    float* Kp = Bm + (size_t)BH * DIM * RP;
    float* Qp = Kp + (size_t)BH * KLEN * RP;
    float* Gpart = Kp;                                // 4 * BH * 128 * 128 floats
    float* Spart = Gpart + (size_t)4 * BH * DIM * DIM; // 4 * BH * 128 floats

    gram_kernel<<<dim3(4, BH), 256, 0, stream>>>(K, Gpart, Spart);
    jacobi_kernel<<<BH, 1024, 0, stream>>>(Gpart, Spart, Bm);
    proj_kernel<<<dim3(KLEN / 64, BH), 256, 0, stream>>>(K, Bm, Kp, KLEN);
    proj_kernel<<<dim3(QLEN / 64, BH), 256, 0, stream>>>(Q, Bm, Qp, QLEN);
    attn_kernel<<<dim3(QLEN / 64, BH), 256, 0, stream>>>(Qp, Kp, V, out);
}

// Round 2
// 2443.546 us; speedup vs baseline: 1.6517x; 1.3554x over previous
//
#include <hip/hip_runtime.h>

#define BH 64
#define KLEN 4096
#define QLEN 512
#define DIM 128
#define RP 32
#define NSWEEP 6

// ---------------- Gram partials: Gpart[c] = Kc^T Kc over chunk c, Spart[c] = col sums ----------------
__global__ __launch_bounds__(256) void gram_kernel(const float* __restrict__ K,
                                                   float* __restrict__ Gpart,
                                                   float* __restrict__ Spart) {
    int bh = blockIdx.y, chunk = blockIdx.x;                  // 4 chunks of 1024 rows
    const float* Kb = K + ((size_t)bh * KLEN + (size_t)chunk * 1024) * DIM;
    __shared__ float Kt[32][129];                             // +1 pad: conflict-free column sums
    int t = threadIdx.x;
    int ty = t >> 4, tx = t & 15;                             // 16x16 threads, each 8x8 tile of C
    float acc[8][8];
#pragma unroll
    for (int i = 0; i < 8; i++)
#pragma unroll
        for (int j = 0; j < 8; j++) acc[i][j] = 0.f;
    float s_acc = 0.f;
    for (int tile = 0; tile < 32; tile++) {
        __syncthreads();
        for (int k = 0; k < 16; k++) {                        // load 32x128 coalesced
            int idx = t + k * 256;
            Kt[idx >> 7][idx & 127] = Kb[tile * 32 * DIM + idx];
        }
        __syncthreads();
#pragma unroll 4
        for (int r = 0; r < 32; r++) {
            float a_[8], b_[8];
#pragma unroll
            for (int i = 0; i < 8; i++) a_[i] = Kt[r][ty * 8 + i];
#pragma unroll
            for (int j = 0; j < 8; j++) b_[j] = Kt[r][tx * 8 + j];
#pragma unroll
            for (int i = 0; i < 8; i++)
#pragma unroll
                for (int j = 0; j < 8; j++) acc[i][j] += a_[i] * b_[j];
        }
        if (t < 128) { float ss = 0.f; for (int r = 0; r < 32; r++) ss += Kt[r][t]; s_acc += ss; }
    }
    // plain stores into this chunk's private slab — no atomics, no zero-init needed
    float* Gb = Gpart + ((size_t)chunk * BH + bh) * DIM * DIM;
#pragma unroll
    for (int i = 0; i < 8; i++)
#pragma unroll
        for (int j = 0; j < 8; j++) Gb[(ty * 8 + i) * DIM + tx * 8 + j] = acc[i][j];
    if (t < 128) Spart[((size_t)chunk * BH + bh) * DIM + t] = s_acc;
}

// ---------------- Jacobi eigensolver, replicated-C / partitioned-Vm version ----------------
// Grid: (4 slices, BH). Each block keeps a full private copy of C (canonical upper triangle
// only) and redundantly runs the sandwich + angle computation — bitwise identical across the
// 4 replicas of a bh, so rank selection agrees. Each block owns a 32-row slice of Vm and
// writes only those rows of Bout. 256 blocks -> all CUs busy; Vm LDS traffic /4; phase-A
// traffic ~halved by symmetry; (p,q) pairings computed arithmetically (no LDS gathers);
// (c,s) packed as float2.
__device__ __forceinline__ void pair_pq(int r, int x, int& p, int& q) {
    if (x == 0) { p = 127; q = r; }
    else {
        int a = r + x;       a -= (a >= 127) ? 127 : 0;
        int b = r + 127 - x; b -= (b >= 127) ? 127 : 0;
        p = a; q = b;
    }
}

__global__ __launch_bounds__(1024) void jacobi_kernel(const float* __restrict__ Gpart,
                                                      const float* __restrict__ Spart,
                                                      float* __restrict__ Bout) {
    __shared__ float C[128][129];    // canonical: only i<=j maintained
    __shared__ float Vm[32][129];    // this block's 32-row slice of the eigenvector matrix
    __shared__ float2 csA[2][64];    // (c,s) per pair, double-buffered
    __shared__ float diag[128];      // summed-S at load time, eigenvalues at the end
    int slice = blockIdx.x, bh = blockIdx.y, t = threadIdx.x;
    const size_t gslab = (size_t)BH * DIM * DIM;
    const float* Gb = Gpart + (size_t)bh * DIM * DIM;

#define CGET(a, b) C[min(a, b)][max(a, b)]

    if (t < 128) {
        float s = 0.f;
#pragma unroll
        for (int c = 0; c < 4; c++) s += Spart[((size_t)c * BH + bh) * DIM + t];
        diag[t] = s;
    }
    __syncthreads();
    for (int k = 0; k < 16; k++) {
        int idx = t + k * 1024;
        int i = idx >> 7, j = idx & 127;
        if (i <= j) {
            float g = Gb[idx] + Gb[gslab + idx] + Gb[2 * gslab + idx] + Gb[3 * gslab + idx];
            C[i][j] = g - diag[i] * diag[j] * (1.0f / 4096.0f);
        }
    }
    for (int k = 0; k < 4; k++) {          // Vm slice = identity rows [32*slice, 32*slice+32)
        int idx = t + k * 1024;
        int kk = idx >> 7, j = idx & 127;
        Vm[kk][j] = (32 * slice + kk == j) ? 1.0f : 0.0f;
    }
    __syncthreads();
    // prologue: angles for round 0
    if (t < 64) {
        int p, q;
        pair_pq(0, t, p, q);
        float app = C[min(p, p)][p], aqq = C[q][q], apq = CGET(p, q);
        float c = 1.0f, s = 0.0f;
        if (apq != 0.0f) {
            float tau = (aqq - app) / (2.0f * apq);
            float root = sqrtf(1.0f + tau * tau);
            float tt = (tau >= 0.0f) ? 1.0f / (tau + root) : 1.0f / (tau - root);
            c = 1.0f / sqrtf(1.0f + tt * tt);
            s = tt * c;
        }
        csA[0][t] = make_float2(c, s);
    }
    __syncthreads();

    // precompute this thread's triangle tasks: ids t, t+1024, (t<32: t+2048)
    // task id < 64  -> diagonal pair (id,id); else strict-upper (i<j) unranked
    int ti0, tj0, ti1, tj1, ti2 = 0, tj2 = 0;
    {
        auto unrank = [](int task, int& i, int& j) {
            if (task < 64) { i = task; j = task; return; }
            int L = task - 64, ii = 0;
            while (L >= 63 - ii) { L -= 63 - ii; ii++; }
            i = ii; j = ii + 1 + L;
        };
        unrank(t, ti0, tj0);
        unrank(t + 1024, ti1, tj1);
        if (t < 32) unrank(t + 2048, ti2, tj2);
    }

    const int NR = NSWEEP * 127;
    int r = 0;                                   // r = sr % 127, maintained incrementally
    for (int sr = 0; sr < NR; sr++) {
        int cur = sr & 1, nxt = cur ^ 1;
        // ---- phase A: sandwich canonical triangle with this round's rotations ----
        {
            auto task = [&](int i, int j) {
                int pi, qi; pair_pq(r, i, pi, qi);
                float2 csi = csA[cur][i];
                if (i == j) {                    // annihilation block: 3 canonical elements
                    float app = C[min(pi, qi)][min(pi, qi)];   // C[p][p] canonical
                    float aqq = C[max(pi, qi)][max(pi, qi)];
                    // careful: app must be C[pi][pi]: recompute plainly
                    app = C[pi][pi]; aqq = C[qi][qi];
                    float apq = CGET(pi, qi);
                    float a1 = csi.x * app - csi.y * apq, b1 = csi.y * app + csi.x * apq;
                    float d1 = csi.x * apq - csi.y * aqq, e1 = csi.y * apq + csi.x * aqq;
                    C[pi][pi] = csi.x * a1 - csi.y * d1;
                    CGET(pi, qi) = csi.x * b1 - csi.y * e1;
                    C[qi][qi] = csi.y * b1 + csi.x * e1;
                } else {
                    int pj, qj; pair_pq(r, j, pj, qj);
                    float2 csj = csA[cur][j];
                    float a = CGET(pi, pj), b = CGET(pi, qj), d = CGET(qi, pj), e = CGET(qi, qj);
                    float a1 = csj.x * a - csj.y * b, b1 = csj.y * a + csj.x * b;
                    float d1 = csj.x * d - csj.y * e, e1 = csj.y * d + csj.x * e;
                    CGET(pi, pj) = csi.x * a1 - csi.y * d1;
                    CGET(qi, pj) = csi.y * a1 + csi.x * d1;
                    CGET(pi, qj) = csi.x * b1 - csi.y * e1;
                    CGET(qi, qj) = csi.y * b1 + csi.x * e1;
                }
            };
            task(ti0, tj0);
            task(ti1, tj1);
            if (t < 32) task(ti2, tj2);
        }
        __syncthreads();
        // ---- phase B: Vm slice rotations (waves 1..15) || next-round angles (wave 0) ----
        if (t < 64) {
            if (sr + 1 < NR) {
                int r2 = (r + 1 == 127) ? 0 : r + 1;
                int p, q;
                pair_pq(r2, t, p, q);
                float app = C[p][p], aqq = C[q][q], apq = CGET(p, q);
                float c = 1.0f, s = 0.0f;
                if (apq != 0.0f) {
                    float tau = (aqq - app) / (2.0f * apq);
                    float root = sqrtf(1.0f + tau * tau);
                    float tt = (tau >= 0.0f) ? 1.0f / (tau + root) : 1.0f / (tau - root);
                    c = 1.0f / sqrtf(1.0f + tt * tt);
                    s = tt * c;
                }
                csA[nxt][t] = make_float2(c, s);
            }
        } else {
            int tt = t - 64;
            for (int tau = tt; tau < 2048; tau += 960) {   // 32 rows x 64 pairs
                int x = tau & 63, k = tau >> 6;
                int pj, qj; pair_pq(r, x, pj, qj);
                float2 cs = csA[cur][x];
                float u = Vm[k][pj], v = Vm[k][qj];
                Vm[k][pj] = cs.x * u - cs.y * v;
                Vm[k][qj] = cs.y * u + cs.x * v;
            }
        }
        __syncthreads();
        r = (r + 1 == 127) ? 0 : r + 1;
    }

    if (t < 128) diag[t] = C[t][t];
    __syncthreads();
    if (t < 128) {   // rank-select top-32 eigenvalues; identical across replicas (bitwise-same C)
        float dt = diag[t];
        int rank = 0;
        for (int j = 0; j < 128; j++) {
            float dj = diag[j];
            rank += (dj > dt) || (dj == dt && j < t);
        }
        if (rank < RP) {
            float* Bb = Bout + (size_t)bh * DIM * RP;
            for (int k = 0; k < 32; k++) Bb[(size_t)(32 * slice + k) * RP + rank] = Vm[k][t];
        }
    }
#undef CGET
}

// ---------------- projection: Y[row][r] = sum_k X[row][k] * B[k][r] ----------------
__global__ __launch_bounds__(256) void proj_kernel(const float* __restrict__ X,
                                                   const float* __restrict__ Bmat,
                                                   float* __restrict__ Y, int nrows) {
    int bh = blockIdx.y, rb = blockIdx.x;
    __shared__ float Bl[128][33];
    __shared__ float Xt[64][129];
    int t = threadIdx.x;
    for (int k = 0; k < 16; k++) {
        int idx = t + k * 256;
        Bl[idx >> 5][idx & 31] = Bmat[(size_t)bh * DIM * RP + idx];
    }
    const float* Xb = X + ((size_t)bh * nrows + (size_t)rb * 64) * DIM;
    for (int k = 0; k < 32; k++) {
        int idx = t + k * 256;
        Xt[idx >> 7][idx & 127] = Xb[idx];
    }
    __syncthreads();
    int row = t >> 2, rg = (t & 3) * 8;
    float acc[8] = {0.f, 0.f, 0.f, 0.f, 0.f, 0.f, 0.f, 0.f};
    for (int k = 0; k < 128; k++) {
        float xv = Xt[row][k];
#pragma unroll
        for (int rr = 0; rr < 8; rr++) acc[rr] += xv * Bl[k][rg + rr];
    }
    float* Yb = Y + ((size_t)bh * nrows + (size_t)rb * 64) * RP + row * RP + rg;
#pragma unroll
    for (int rr = 0; rr < 8; rr++) Yb[rr] = acc[rr];
}

// ---------------- fused flash-style attention: softmax(Qp Kp^T * scale) @ V ----------------
__global__ __launch_bounds__(256, 2) void attn_kernel(const float* __restrict__ Qp,
                                                      const float* __restrict__ Kp,
                                                      const float* __restrict__ Vg,
                                                      float* __restrict__ Out) {
    const float SCALE = 0.1767766953f;  // 1/sqrt(32)
    int qt = blockIdx.x, bh = blockIdx.y;
    __shared__ float Kpl[128][36];      // rows of 32 floats, stride 36 (144 B, 16B aligned)
    __shared__ float Vt[32][132];       // quarter V tile, stride 132 (528 B, 16B aligned)
    __shared__ float Sl[64][132];       // weights exchange, (4q+j)%32 banks -> 2-way max
    int t = threadIdx.x;
    int q = t >> 2, g = t & 3;          // 64 queries x 4 lanes per query
    float qreg[32];
    const float* Qb = Qp + ((size_t)bh * QLEN + (size_t)qt * 64 + q) * RP;
#pragma unroll
    for (int r = 0; r < 32; r++) qreg[r] = Qb[r];
    float acc[32];                      // dims d = i4*16 + g*4 + c
#pragma unroll
    for (int i = 0; i < 32; i++) acc[i] = 0.f;
    float m_run = -INFINITY, l_run = 0.0f;   // replicated across the 4 g-lanes

    for (int kt = 0; kt < 32; kt++) {
        __syncthreads();
        const float4* Kpb = (const float4*)(Kp + ((size_t)bh * KLEN + (size_t)kt * 128) * RP);
        for (int k = 0; k < 4; k++) {
            int idx4 = t + k * 256;
            int j = idx4 >> 3, r4 = idx4 & 7;
            *(float4*)&Kpl[j][r4 * 4] = Kpb[idx4];
        }
        __syncthreads();
        // ---- scores in registers: thread (q,g) owns kv j = jj*4+g ----
        float sreg[32];
#pragma unroll
        for (int jj = 0; jj < 32; jj++) {
            int j = jj * 4 + g;
            float s = 0.f;
#pragma unroll
            for (int r4 = 0; r4 < 8; r4++) {
                float4 kv = *(const float4*)&Kpl[j][r4 * 4];
                s += qreg[r4 * 4 + 0] * kv.x + qreg[r4 * 4 + 1] * kv.y
                   + qreg[r4 * 4 + 2] * kv.z + qreg[r4 * 4 + 3] * kv.w;
            }
            sreg[jj] = s * SCALE;
        }
        // ---- online softmax, register + 4-lane shuffle reduce ----
        float mx = sreg[0];
#pragma unroll
        for (int jj = 1; jj < 32; jj++) mx = fmaxf(mx, sreg[jj]);
        mx = fmaxf(mx, __shfl_xor(mx, 1));
        mx = fmaxf(mx, __shfl_xor(mx, 2));
        float m_new = fmaxf(m_run, mx);
        float alpha = __expf(m_run - m_new);    // first tile: exp(-inf)=0
        float psum = 0.f;
#pragma unroll
        for (int jj = 0; jj < 32; jj++) {
            float w = __expf(sreg[jj] - m_new);
            sreg[jj] = w;
            psum += w;
        }
        psum += __shfl_xor(psum, 1);
        psum += __shfl_xor(psum, 2);
        l_run = l_run * alpha + psum;
        m_run = m_new;
        // publish weights for the kv<->dim exchange
#pragma unroll
        for (int jj = 0; jj < 32; jj++) Sl[q][jj * 4 + g] = sreg[jj];
#pragma unroll
        for (int i = 0; i < 32; i++) acc[i] *= alpha;
        // ---- PV: V staged in 4 quarter-tiles of 32 kv rows ----
        for (int ss = 0; ss < 4; ss++) {
            __syncthreads();   // (also covers Sl visibility on ss==0)
            const float4* Vb = (const float4*)(Vg + ((size_t)bh * KLEN + (size_t)kt * 128 + (size_t)ss * 32) * DIM);
            for (int k = 0; k < 4; k++) {
                int idx4 = t + k * 256;
                int j = idx4 >> 5, c4 = idx4 & 31;
                *(float4*)&Vt[j][c4 * 4] = Vb[idx4];
            }
            __syncthreads();
            for (int j = 0; j < 32; j++) {
                float w = Sl[q][ss * 32 + j];
#pragma unroll
                for (int i4 = 0; i4 < 8; i4++) {
                    float4 vv = *(const float4*)&Vt[j][i4 * 16 + g * 4];
                    acc[i4 * 4 + 0] += w * vv.x;
                    acc[i4 * 4 + 1] += w * vv.y;
                    acc[i4 * 4 + 2] += w * vv.z;
                    acc[i4 * 4 + 3] += w * vv.w;
                }
            }
        }
    }
    float linv = 1.0f / l_run;
    float* Ob = Out + ((size_t)bh * QLEN + (size_t)qt * 64 + q) * DIM;
#pragma unroll
    for (int i4 = 0; i4 < 8; i4++) {
        float4 o;
        o.x = acc[i4 * 4 + 0] * linv;
        o.y = acc[i4 * 4 + 1] * linv;
        o.z = acc[i4 * 4 + 2] * linv;
        o.w = acc[i4 * 4 + 3] * linv;
        *(float4*)&Ob[i4 * 16 + g * 4] = o;
    }
}

extern "C" void kernel_launch(void* const* d_in, const int* in_sizes, int n_in,
                              void* d_out, int out_size, void* d_ws, size_t ws_size,
                              hipStream_t stream) {
    const float* Q = (const float*)d_in[0];
    const float* K = (const float*)d_in[1];
    const float* V = (const float*)d_in[2];
    float* out = (float*)d_out;
    float* ws = (float*)d_ws;
    // workspace layout (floats):
    //   G 1048576 | S 8192 | B 262144 | Kp 8388608 | Qp 1048576   (same 43 MB footprint as before)
    // Gram partials (4 slabs G + 4 slabs S = 4227072 floats) live INSIDE the Kp region,
    // which is only written later by proj_kernel — no extra workspace needed, no atomics, no zeroing.
    float* G  = ws;                                   // unused this round (kept for layout stability)
    float* S  = G + (size_t)BH * DIM * DIM;
    float* Bm = S + BH * DIM;
    float* Kp = Bm + (size_t)BH * DIM * RP;
    float* Qp = Kp + (size_t)BH * KLEN * RP;
    float* Gpart = Kp;                                // 4 * BH * 128 * 128 floats
    float* Spart = Gpart + (size_t)4 * BH * DIM * DIM; // 4 * BH * 128 floats

    gram_kernel<<<dim3(4, BH), 256, 0, stream>>>(K, Gpart, Spart);
    jacobi_kernel<<<dim3(4, BH), 1024, 0, stream>>>(Gpart, Spart, Bm);
    proj_kernel<<<dim3(KLEN / 64, BH), 256, 0, stream>>>(K, Bm, Kp, KLEN);
    proj_kernel<<<dim3(QLEN / 64, BH), 256, 0, stream>>>(Q, Bm, Qp, QLEN);
    attn_kernel<<<dim3(QLEN / 64, BH), 256, 0, stream>>>(Qp, Kp, V, out);
}